// Round 6
// baseline (732.365 us; speedup 1.0000x reference)
//
#include <hip/hip_runtime.h>
#include <cstdint>
#include <cstddef>

#define B_ROWS 16384
#define D_DIM  512
#define NTXT_N 4096
#define H_DIM  1024

typedef __attribute__((ext_vector_type(8))) short short8;
typedef __attribute__((ext_vector_type(4))) float f32x4;

__device__ __forceinline__ ushort f2bf(float x) {
    union { float f; uint32_t u; } c; c.f = x;
    const uint32_t u = c.u;
    return (ushort)((u + 0x7fffu + ((u >> 16) & 1u)) >> 16);   // RNE
}
__device__ __forceinline__ float bf2f(ushort h) {
    union { uint32_t u; float f; } c; c.u = ((uint32_t)h) << 16;
    return c.f;
}

#define GLDS16(gp, lp) __builtin_amdgcn_global_load_lds( \
    (const __attribute__((address_space(1))) void*)(gp),  \
    (__attribute__((address_space(3))) void*)(lp), 16, 0, 0)

// bijective XCD-aware block remap (T1, m204 formula; MI355X = 8 XCDs)
__device__ __forceinline__ void xcd_remap(int& bx, int& by) {
    const int nx = gridDim.x, ny = gridDim.y;
    const int nwg = nx * ny;
    const int bid = by * nx + bx;
    const int q = nwg >> 3, r = nwg & 7;
    const int xcd = bid & 7, idx = bid >> 3;
    const int nb = (xcd < r ? xcd * (q + 1) : r * (q + 1) + (xcd - r) * q) + idx;
    bx = nb % nx; by = nb / nx;
}

// ---------------- init ----------------
__global__ void init_kernel(int* acc) {
    if (threadIdx.x == 0 && blockIdx.x == 0) *acc = 0;
}

// ---------------- transpose + split:  in[R][C] -> out[C-chunk][R] (hi,lo bf16) ----------------
__global__ void tsplit_kernel(const float* __restrict__ in, ushort* __restrict__ oh,
                              ushort* __restrict__ ol, int R, int C, int cbase)
{
    __shared__ float tile[32][33];
    const int c0 = blockIdx.x * 32, r0 = blockIdx.y * 32;
    const int tx = threadIdx.x, ty = threadIdx.y;   // (32,8)
    #pragma unroll
    for (int j = 0; j < 32; j += 8)
        tile[ty + j][tx] = in[(size_t)(r0 + ty + j) * C + cbase + c0 + tx];
    __syncthreads();
    #pragma unroll
    for (int j = 0; j < 32; j += 8) {
        const float v = tile[tx][ty + j];
        const ushort h = f2bf(v);
        const size_t idx = (size_t)(c0 + ty + j) * R + r0 + tx;
        oh[idx] = h;
        ol[idx] = f2bf(v - bf2f(h));
    }
}

// ---------------- straight split: f32[n] -> hi,lo bf16[n] ----------------
__global__ void csplit_kernel(const float* __restrict__ in, ushort* __restrict__ oh,
                              ushort* __restrict__ ol, int n)
{
    const int i = (blockIdx.x * 256 + threadIdx.x) * 4;
    if (i >= n) return;
    const float4 f = *(const float4*)&in[i];
    ushort4 h, l;
    h.x = f2bf(f.x); l.x = f2bf(f.x - bf2f(h.x));
    h.y = f2bf(f.y); l.y = f2bf(f.y - bf2f(h.y));
    h.z = f2bf(f.z); l.z = f2bf(f.z - bf2f(h.z));
    h.w = f2bf(f.w); l.w = f2bf(f.w - bf2f(h.w));
    *(ushort4*)&oh[i] = h;
    *(ushort4*)&ol[i] = l;
}

// ---------------- weight pack: Wf[K,N] f32 -> fragment-major packed hi/lo ----------------
// packed[nb][t][lane][8]: lane = frow + 16*kslot holds B^T[col=nb*16+frow][k=t*32+kslot*8+j]
// = Wf[t*32+kslot*8+j][nb*16+frow].  One wave b-frag load = coalesced 1KB.
__global__ void wpack_kernel(const float* __restrict__ in, ushort* __restrict__ oh,
                             ushort* __restrict__ ol, int K, int N)
{
    __shared__ float tile[32][33];
    const int n0 = blockIdx.x * 32, k0 = blockIdx.y * 32;
    const int tid = threadIdx.x;                 // 256
    const int r = tid >> 3, c4 = (tid & 7) << 2;
    const float4 f = *(const float4*)&in[(size_t)(k0 + r) * N + n0 + c4];
    tile[r][c4 + 0] = f.x; tile[r][c4 + 1] = f.y; tile[r][c4 + 2] = f.z; tile[r][c4 + 3] = f.w;
    __syncthreads();
    const int hl = tid & 1, lane = (tid >> 1) & 63, nbl = tid >> 7;
    const int frow = lane & 15, ks = lane >> 4;
    short8 v;
    #pragma unroll
    for (int j = 0; j < 8; ++j) {
        const float x = tile[ks * 8 + j][nbl * 16 + frow];
        const ushort h = f2bf(x);
        v[j] = (short)(hl ? f2bf(x - bf2f(h)) : h);
    }
    const size_t dst = (((size_t)(n0 / 16 + nbl) * (K >> 5) + (k0 >> 5)) * 64 + lane) * 8;
    *(short8*)&((hl ? ol : oh)[dst]) = v;
}

// ---------------- MFMA split-bf16 GEMM: A via LDS, B direct from packed global ----------------
// C[M,N] = act( (Ah+Al)[M,K] @ (Bh+Bl)^T (+bias) ),  3-pass: AhBh + AhBl + AlBh.
// 128x128 tile, BK=32, 256 thr (4 waves 2x2), 4x4 16x16x32 frags/wave.
// A: double-buffered LDS (32 KiB total), global_load_lds, 1 barrier/K-step,
//    stage(t+1) overlaps compute(t).  Slot-swizzle (0-conflict, r3-verified).
// B: fragment-major packed (see wpack) -> coalesced global_load_dwordx4 per frag,
//    L2-resident (weights <=4MB, p_txt 8MB).  No LDS, no barrier dependency.
// OMODE 0: f32 to Cf.  1: hi/lo row-major to Ch/Cl.  2: hi/lo fragment-packed
//    (rows offset by rowoff) to Ch/Cl — output directly usable as next B.
template<int K, int OMODE, bool RELU, bool BIAS>
__global__ __launch_bounds__(256, 3)
void gemm_bd_kernel(const ushort* __restrict__ Ah, const ushort* __restrict__ Al,
                    const ushort* __restrict__ PBh, const ushort* __restrict__ PBl,
                    const float* __restrict__ bias,
                    float* __restrict__ Cf, ushort* __restrict__ Ch, ushort* __restrict__ Cl,
                    int rowoff, int M, int N)
{
    constexpr int NT = K / 32;                       // K-steps
    __shared__ __align__(16) ushort LDSB[2 * 8192];  // 32 KiB: [buf][Ah 4096 | Al 4096]

    const int tid  = threadIdx.x;
    const int lane = tid & 63;
    const int w    = tid >> 6;
    const int wr   = w >> 1, wc = w & 1;

    int bxi = blockIdx.x, byi = blockIdx.y;
    xcd_remap(bxi, byi);
    const int bm = byi * 128, bn = bxi * 128;
    const int bnb = bn >> 4;                         // base n-frag index for packed B

    // A staging: lane l -> LDS (row = w*32 + j*16 + (l>>2), phys slot = l&3);
    // global slot = (l&3) ^ ((l>>3)&3)  [source pre-swizzle, rule #21]
    const int    stlo  = w * 1024;
    const int    srow  = w * 32 + (lane >> 2);
    const int    scol  = (((lane & 3) ^ ((lane >> 3) & 3)) << 3);
    const size_t aoff0 = (size_t)(bm + srow) * K + scol;

    // A fragment-read swizzle (0-conflict verified)
    const int frow = lane & 15;
    const int koff = ((lane >> 4) ^ ((frow >> 1) & 3)) << 3;

    f32x4 acc[4][4];
    #pragma unroll
    for (int m = 0; m < 4; ++m)
        #pragma unroll
        for (int n = 0; n < 4; ++n)
            acc[m][n] = (f32x4)0.0f;

#define STAGE(tt, bi) do {                                                    \
        const int _kk = (tt) * 32;                                            \
        ushort* _b = &LDSB[(bi) * 8192];                                      \
        GLDS16(Ah + aoff0 + _kk,          _b +        stlo);                  \
        GLDS16(Ah + aoff0 + _kk + 16 * K, _b +        stlo + 512);            \
        GLDS16(Al + aoff0 + _kk,          _b + 4096 + stlo);                  \
        GLDS16(Al + aoff0 + _kk + 16 * K, _b + 4096 + stlo + 512);            \
    } while (0)

#define COMPUTE(tt, bi) do {                                                  \
        const ushort* _Ahs = &LDSB[(bi) * 8192];                              \
        const ushort* _Als = _Ahs + 4096;                                     \
        short8 a_h[4], a_l[4], b_h[4], b_l[4];                                \
        _Pragma("unroll")                                                     \
        for (int n = 0; n < 4; ++n) {                                         \
            const size_t bidx =                                               \
                (((size_t)(bnb + wc * 4 + n) * NT + (tt)) * 64 + lane) * 8;   \
            b_h[n] = *(const short8*)&PBh[bidx];                              \
            b_l[n] = *(const short8*)&PBl[bidx];                              \
        }                                                                     \
        _Pragma("unroll")                                                     \
        for (int m = 0; m < 4; ++m) {                                         \
            const int off = (wr * 64 + m * 16 + frow) * 32 + koff;            \
            a_h[m] = *(const short8*)&_Ahs[off];                              \
            a_l[m] = *(const short8*)&_Als[off];                              \
        }                                                                     \
        __builtin_amdgcn_s_setprio(1);                                        \
        _Pragma("unroll")                                                     \
        for (int m = 0; m < 4; ++m)                                           \
            _Pragma("unroll")                                                 \
            for (int n = 0; n < 4; ++n) {                                     \
                acc[m][n] = __builtin_amdgcn_mfma_f32_16x16x32_bf16(          \
                    a_h[m], b_h[n], acc[m][n], 0, 0, 0);                      \
                acc[m][n] = __builtin_amdgcn_mfma_f32_16x16x32_bf16(          \
                    a_h[m], b_l[n], acc[m][n], 0, 0, 0);                      \
                acc[m][n] = __builtin_amdgcn_mfma_f32_16x16x32_bf16(          \
                    a_l[m], b_h[n], acc[m][n], 0, 0, 0);                      \
            }                                                                 \
        __builtin_amdgcn_s_setprio(0);                                        \
    } while (0)

    STAGE(0, 0);
    #pragma unroll 2
    for (int t = 0; t < NT; ++t) {
        __syncthreads();                       // A tile t ready; buf[(t+1)&1] free
        if (t + 1 < NT) STAGE(t + 1, (t + 1) & 1);   // overlaps compute(t)
        COMPUTE(t, t & 1);
    }

#undef STAGE
#undef COMPUTE

    // epilogue: C/D layout col = lane&15, row = (lane>>4)*4 + q
    const int crow0 = bm + wr * 64 + (lane >> 4) * 4;
    const int ccol0 = bn + wc * 64 + (lane & 15);
    const int NTo = N >> 5;
    #pragma unroll
    for (int m = 0; m < 4; ++m)
        #pragma unroll
        for (int n = 0; n < 4; ++n) {
            const int col = ccol0 + n * 16;
            const float bv = BIAS ? bias[col] : 0.0f;
            #pragma unroll
            for (int q = 0; q < 4; ++q) {
                float v = acc[m][n][q] + bv;
                if (RELU) v = fmaxf(v, 0.0f);
                if (OMODE == 0) {
                    Cf[(size_t)(crow0 + m * 16 + q) * N + col] = v;
                } else if (OMODE == 1) {
                    const size_t idx = (size_t)(crow0 + m * 16 + q) * N + col;
                    const ushort h = f2bf(v);
                    Ch[idx] = h;
                    Cl[idx] = f2bf(v - bf2f(h));
                } else {
                    // fragment-packed write: this output is the next GEMM's B
                    const int gr = rowoff + crow0 + m * 16 + q;   // B row (n dim)
                    const int nb2 = gr >> 4, fr2 = gr & 15;
                    const int tt2 = col >> 5, ks2 = (col >> 3) & 3, jj = col & 7;
                    const size_t pidx =
                        (((size_t)nb2 * NTo + tt2) * 64 + fr2 + (ks2 << 4)) * 8 + jj;
                    const ushort h = f2bf(v);
                    Ch[pidx] = h;
                    Cl[pidx] = f2bf(v - bf2f(h));
                }
            }
        }
}

// ---------------- per-row reduction over one sim chunk ----------------
__global__ __launch_bounds__(256) void rowreduce_kernel(
    const float* __restrict__ sim, const int* __restrict__ tgt,
    const float* __restrict__ temp_p, float* __restrict__ perrow,
    int* __restrict__ acc_cnt, int row0)
{
    const int row = blockIdx.x;
    const float* srow = sim + (size_t)row * NTXT_N;
    const int tid = threadIdx.x;

    float v[16];
    #pragma unroll
    for (int q = 0; q < 4; ++q) {
        float4 f = *(const float4*)&srow[4 * tid + 1024 * q];
        v[4 * q + 0] = f.x; v[4 * q + 1] = f.y; v[4 * q + 2] = f.z; v[4 * q + 3] = f.w;
    }

    float ss = 0.0f, mx = -3.4e38f; int mi = 0x7fffffff;
    #pragma unroll
    for (int q = 0; q < 4; ++q)
        #pragma unroll
        for (int r = 0; r < 4; ++r) {
            const int j = 4 * tid + 1024 * q + r;
            const float x = v[4 * q + r];
            ss = fmaf(x, x, ss);
            if (x > mx) { mx = x; mi = j; }
            else if (x == mx && j < mi) mi = j;
        }

    #pragma unroll
    for (int off = 32; off; off >>= 1) {
        ss += __shfl_down(ss, off);
        const float omx = __shfl_down(mx, off);
        const int   omi = __shfl_down(mi, off);
        if (omx > mx || (omx == mx && omi < mi)) { mx = omx; mi = omi; }
    }

    __shared__ float sws[4], swm[4];
    __shared__ int   swi[4];
    __shared__ float bC, bMx;
    __shared__ int   bAmax;
    const int w = tid >> 6, lane = tid & 63;
    if (lane == 0) { sws[w] = ss; swm[w] = mx; swi[w] = mi; }
    __syncthreads();
    if (tid == 0) {
        float tss = 0.0f, tmx = -3.4e38f; int tmi = 0x7fffffff;
        #pragma unroll
        for (int i = 0; i < 4; ++i) {
            tss += sws[i];
            if (swm[i] > tmx || (swm[i] == tmx && swi[i] < tmi)) { tmx = swm[i]; tmi = swi[i]; }
        }
        const float inv_nr = 1.0f / sqrtf(tss);
        const float n2 = sqrtf(tss * inv_nr * inv_nr);   // ~= 1, faithful to reference
        const float Cv = inv_nr / (n2 * temp_p[0]);
        bC = Cv; bMx = tmx * Cv; bAmax = tmi;
    }
    __syncthreads();
    const float Cv = bC, mxx = bMx;

    float es = 0.0f;
    #pragma unroll
    for (int q = 0; q < 16; ++q) es += expf(v[q] * Cv - mxx);
    #pragma unroll
    for (int off = 32; off; off >>= 1) es += __shfl_down(es, off);
    if (lane == 0) sws[w] = es;
    __syncthreads();
    if (tid == 0) {
        const float tes = sws[0] + sws[1] + sws[2] + sws[3];
        const float lse = mxx + logf(tes);
        const int t = tgt[row0 + row];
        perrow[row0 + row] = lse - srow[t] * Cv;
        if (bAmax == t) atomicAdd(acc_cnt, 1);
    }
}

// ---------------- finalize ----------------
__global__ __launch_bounds__(256) void finalize_kernel(
    const float* __restrict__ perrow, const int* __restrict__ acc_cnt,
    float* __restrict__ out)
{
    __shared__ float red[256];
    const int tid = threadIdx.x;
    float s = 0.0f;
    for (int i = tid; i < B_ROWS; i += 256) s += perrow[i];
    red[tid] = s;
    __syncthreads();
    for (int st = 128; st; st >>= 1) {
        if (tid < st) red[tid] += red[tid + st];
        __syncthreads();
    }
    if (tid == 0) {
        out[0] = red[0] / (float)B_ROWS;
        out[1] = (float)(*acc_cnt);
    }
}

extern "C" void kernel_launch(void* const* d_in, const int* in_sizes, int n_in,
                              void* d_out, int out_size, void* d_ws, size_t ws_size,
                              hipStream_t stream)
{
    const float* img  = (const float*)d_in[0];
    const float* txt  = (const float*)d_in[1];
    const int*   tgt  = (const int*)  d_in[2];
    const float* temp = (const float*)d_in[3];
    const float* Wf[6] = { (const float*)d_in[4],  (const float*)d_in[6],  (const float*)d_in[8],
                           (const float*)d_in[10], (const float*)d_in[12], (const float*)d_in[14] };
    const float* bf[6] = { (const float*)d_in[5],  (const float*)d_in[7],  (const float*)d_in[9],
                           (const float*)d_in[11], (const float*)d_in[13], (const float*)d_in[15] };
    float* out = (float*)d_out;

    // weight shapes [K, N]; packed as fragment-major [N/16][K/32][64][8] hi/lo
    const int wK[6] = { D_DIM, H_DIM, H_DIM, D_DIM, H_DIM, H_DIM };
    const int wN[6] = { H_DIM, H_DIM, D_DIM, H_DIM, H_DIM, D_DIM };

    // ---- choose chunk sizes: prefer big M for occupancy ----
    auto need = [&](size_t ch, size_t sc) -> size_t {
        size_t wt = 0;
        for (int i = 0; i < 6; ++i) wt += (size_t)wK[i] * wN[i] * 2 * 2;
        const size_t a01 = 2 * (ch * H_DIM * 2 * 2);
        const size_t pt  = (size_t)NTXT_N * D_DIM * 2 * 2;
        const size_t sim = sc * NTXT_N * 4;
        return wt + a01 + pt + sim + (size_t)B_ROWS * 4 + (size_t)64 * 1024;
    };
    const size_t ladder[][2] = { {16384, 4096}, {16384, 2048}, {8192, 4096}, {8192, 2048},
                                 {4096, 2048},  {4096, 1024},  {2048, 1024}, {1024, 1024} };
    size_t CH = 1024, SIMCH = 512;
    for (auto& e : ladder)
        if (need(e[0], e[1]) <= ws_size) { CH = e[0]; SIMCH = e[1]; break; }

    // ---- carve workspace ----
    uint8_t* p = (uint8_t*)d_ws;
    auto alloc = [&](size_t bytes) -> void* {
        void* r = (void*)p; p += (bytes + 255) & ~(size_t)255; return r;
    };
    ushort* PWh[6]; ushort* PWl[6];
    for (int i = 0; i < 6; ++i) {
        PWh[i] = (ushort*)alloc((size_t)wK[i] * wN[i] * 2);
        PWl[i] = (ushort*)alloc((size_t)wK[i] * wN[i] * 2);
    }
    ushort* A0h = (ushort*)alloc(CH * H_DIM * 2);
    ushort* A0l = (ushort*)alloc(CH * H_DIM * 2);
    ushort* A1h = (ushort*)alloc(CH * H_DIM * 2);
    ushort* A1l = (ushort*)alloc(CH * H_DIM * 2);
    ushort* PTh = (ushort*)alloc((size_t)NTXT_N * D_DIM * 2);   // packed p_txt
    ushort* PTl = (ushort*)alloc((size_t)NTXT_N * D_DIM * 2);
    float*  SIM = (float*)alloc(SIMCH * NTXT_N * 4);
    float*  PERROW = (float*)alloc((size_t)B_ROWS * 4);
    int*    ACC = (int*)alloc(64);
    ushort* XBh = A1h;  ushort* XBl = A1l;      // input chunk alias
    ushort* PIh = A0h;  ushort* PIl = A0l;      // p_img chunk alias

    init_kernel<<<1, 64, 0, stream>>>(ACC);

    // ---- weight pack (fragment-major hi/lo) ----
    for (int i = 0; i < 6; ++i)
        wpack_kernel<<<dim3(wN[i] / 32, wK[i] / 32), 256, 0, stream>>>(
            Wf[i], PWh[i], PWl[i], wK[i], wN[i]);

    // ---- txt MLP: p_txt = MLP(txt^T), chunked; L3 writes fragment-packed ----
    const size_t CHT = CH < (size_t)NTXT_N ? CH : (size_t)NTXT_N;
    for (size_t n0 = 0; n0 < NTXT_N; n0 += CHT) {
        tsplit_kernel<<<dim3(CHT / 32, D_DIM / 32), dim3(32, 8), 0, stream>>>(
            txt, XBh, XBl, D_DIM, NTXT_N, (int)n0);
        gemm_bd_kernel<D_DIM, 1, true, true><<<dim3(H_DIM / 128, CHT / 128), 256, 0, stream>>>(
            XBh, XBl, PWh[3], PWl[3], bf[3], nullptr, A0h, A0l, 0, (int)CHT, H_DIM);
        gemm_bd_kernel<H_DIM, 1, true, true><<<dim3(H_DIM / 128, CHT / 128), 256, 0, stream>>>(
            A0h, A0l, PWh[4], PWl[4], bf[4], nullptr, A1h, A1l, 0, (int)CHT, H_DIM);
        gemm_bd_kernel<H_DIM, 2, false, true><<<dim3(D_DIM / 128, CHT / 128), 256, 0, stream>>>(
            A1h, A1l, PWh[5], PWl[5], bf[5], nullptr, PTh, PTl, (int)n0, (int)CHT, D_DIM);
    }

    // ---- img MLP + fused sim/loss, chunked ----
    for (size_t m0 = 0; m0 < B_ROWS; m0 += CH) {
        csplit_kernel<<<(CH * D_DIM / 4 + 255) / 256, 256, 0, stream>>>(
            img + m0 * D_DIM, XBh, XBl, (int)(CH * D_DIM));
        gemm_bd_kernel<D_DIM, 1, true, true><<<dim3(H_DIM / 128, CH / 128), 256, 0, stream>>>(
            XBh, XBl, PWh[0], PWl[0], bf[0], nullptr, A0h, A0l, 0, (int)CH, H_DIM);
        gemm_bd_kernel<H_DIM, 1, true, true><<<dim3(H_DIM / 128, CH / 128), 256, 0, stream>>>(
            A0h, A0l, PWh[1], PWl[1], bf[1], nullptr, A1h, A1l, 0, (int)CH, H_DIM);
        gemm_bd_kernel<H_DIM, 1, false, true><<<dim3(D_DIM / 128, CH / 128), 256, 0, stream>>>(
            A1h, A1l, PWh[2], PWl[2], bf[2], nullptr, PIh, PIl, 0, (int)CH, D_DIM);
        for (size_t s0 = 0; s0 < CH; s0 += SIMCH) {
            gemm_bd_kernel<D_DIM, 0, false, false><<<dim3(NTXT_N / 128, SIMCH / 128), 256, 0, stream>>>(
                PIh + s0 * D_DIM, PIl + s0 * D_DIM, PTh, PTl, nullptr,
                SIM, nullptr, nullptr, 0, (int)SIMCH, NTXT_N);
            rowreduce_kernel<<<SIMCH, 256, 0, stream>>>(
                SIM, tgt, temp, PERROW, ACC, (int)(m0 + s0));
        }
    }

    finalize_kernel<<<1, 256, 0, stream>>>(PERROW, ACC, out);
}

// Round 7
// 659.689 us; speedup vs baseline: 1.1102x; 1.1102x over previous
//
#include <hip/hip_runtime.h>
#include <cstdint>
#include <cstddef>

#define B_ROWS 16384
#define D_DIM  512
#define NTXT_N 4096
#define H_DIM  1024

typedef __attribute__((ext_vector_type(8))) short short8;
typedef __attribute__((ext_vector_type(4))) float f32x4;

__device__ __forceinline__ ushort f2bf(float x) {
    union { float f; uint32_t u; } c; c.f = x;
    const uint32_t u = c.u;
    return (ushort)((u + 0x7fffu + ((u >> 16) & 1u)) >> 16);   // RNE
}
__device__ __forceinline__ float bf2f(ushort h) {
    union { uint32_t u; float f; } c; c.u = ((uint32_t)h) << 16;
    return c.f;
}

#define GLDS16(gp, lp) __builtin_amdgcn_global_load_lds( \
    (const __attribute__((address_space(1))) void*)(gp),  \
    (__attribute__((address_space(3))) void*)(lp), 16, 0, 0)

// bijective XCD-aware block remap (T1, m204 formula; MI355X = 8 XCDs)
__device__ __forceinline__ void xcd_remap(int& bx, int& by) {
    const int nx = gridDim.x, ny = gridDim.y;
    const int nwg = nx * ny;
    const int bid = by * nx + bx;
    const int q = nwg >> 3, r = nwg & 7;
    const int xcd = bid & 7, idx = bid >> 3;
    const int nb = (xcd < r ? xcd * (q + 1) : r * (q + 1) + (xcd - r) * q) + idx;
    bx = nb % nx; by = nb / nx;
}

// ---------------- init ----------------
__global__ void init_kernel(int* acc) {
    if (threadIdx.x == 0 && blockIdx.x == 0) *acc = 0;
}

// ---------------- transpose + split:  in[R][C] -> out[C-chunk][R] (hi,lo bf16) ----------------
__global__ void tsplit_kernel(const float* __restrict__ in, ushort* __restrict__ oh,
                              ushort* __restrict__ ol, int R, int C, int cbase)
{
    __shared__ float tile[32][33];
    const int c0 = blockIdx.x * 32, r0 = blockIdx.y * 32;
    const int tx = threadIdx.x, ty = threadIdx.y;   // (32,8)
    #pragma unroll
    for (int j = 0; j < 32; j += 8)
        tile[ty + j][tx] = in[(size_t)(r0 + ty + j) * C + cbase + c0 + tx];
    __syncthreads();
    #pragma unroll
    for (int j = 0; j < 32; j += 8) {
        const float v = tile[tx][ty + j];
        const ushort h = f2bf(v);
        const size_t idx = (size_t)(c0 + ty + j) * R + r0 + tx;
        oh[idx] = h;
        ol[idx] = f2bf(v - bf2f(h));
    }
}

// ---------------- straight split: f32[n] -> hi,lo bf16[n] ----------------
__global__ void csplit_kernel(const float* __restrict__ in, ushort* __restrict__ oh,
                              ushort* __restrict__ ol, int n)
{
    const int i = (blockIdx.x * 256 + threadIdx.x) * 4;
    if (i >= n) return;
    const float4 f = *(const float4*)&in[i];
    ushort4 h, l;
    h.x = f2bf(f.x); l.x = f2bf(f.x - bf2f(h.x));
    h.y = f2bf(f.y); l.y = f2bf(f.y - bf2f(h.y));
    h.z = f2bf(f.z); l.z = f2bf(f.z - bf2f(h.z));
    h.w = f2bf(f.w); l.w = f2bf(f.w - bf2f(h.w));
    *(ushort4*)&oh[i] = h;
    *(ushort4*)&ol[i] = l;
}

// ================= 128x128 split-bf16 GEMM (r5-verified) =================
// C[M,N] = act( (Ah+Al)[M,K] @ (Bh+Bl)^T[N,K] (+bias) ),  3-pass split.
// 2-phase pipeline, double-buffered 64 KiB LDS, 0-conflict slot swizzle.
template<int K, int OMODE, bool RELU, bool BIAS>
__global__ __launch_bounds__(256, 2)
void gemm_p2_kernel(const ushort* __restrict__ Ah, const ushort* __restrict__ Al,
                    const ushort* __restrict__ Bh, const ushort* __restrict__ Bl,
                    const float* __restrict__ bias,
                    float* __restrict__ Cf, ushort* __restrict__ Ch, ushort* __restrict__ Cl,
                    int M, int N)
{
    constexpr int NT = K / 32;
    __shared__ __align__(16) ushort LDSB[2 * 4 * 4096];   // 64 KiB

    const int tid  = threadIdx.x;
    const int lane = tid & 63;
    const int w    = tid >> 6;
    const int wr   = w >> 1, wc = w & 1;

    int bxi = blockIdx.x, byi = blockIdx.y;
    xcd_remap(bxi, byi);
    const int bm = byi * 128, bn = bxi * 128;

    const int    stlo  = w * 1024;
    const int    srow  = w * 32 + (lane >> 2);
    const int    scol  = (((lane & 3) ^ ((lane >> 3) & 3)) << 3);
    const size_t aoff0 = (size_t)(bm + srow) * K + scol;
    const size_t boff0 = (size_t)(bn + srow) * K + scol;

    const int frow = lane & 15;
    const int koff = ((lane >> 4) ^ ((frow >> 1) & 3)) << 3;

    f32x4 acc[4][4];
    #pragma unroll
    for (int m = 0; m < 4; ++m)
        #pragma unroll
        for (int n = 0; n < 4; ++n)
            acc[m][n] = (f32x4)0.0f;

#define STAGE(tt, bi) do {                                                    \
        const int _kk = (tt) * 32;                                            \
        ushort* _b = &LDSB[(bi) * 16384];                                     \
        GLDS16(Ah + aoff0 + _kk,          _b +         stlo);                 \
        GLDS16(Ah + aoff0 + _kk + 16 * K, _b +         stlo + 512);           \
        GLDS16(Al + aoff0 + _kk,          _b +  4096 + stlo);                 \
        GLDS16(Al + aoff0 + _kk + 16 * K, _b +  4096 + stlo + 512);           \
        GLDS16(Bh + boff0 + _kk,          _b +  8192 + stlo);                 \
        GLDS16(Bh + boff0 + _kk + 16 * K, _b +  8192 + stlo + 512);           \
        GLDS16(Bl + boff0 + _kk,          _b + 12288 + stlo);                 \
        GLDS16(Bl + boff0 + _kk + 16 * K, _b + 12288 + stlo + 512);           \
    } while (0)

#define COMPUTE(bi) do {                                                      \
        const ushort* _Ahs = &LDSB[(bi) * 16384];                             \
        const ushort* _Als = _Ahs + 4096;                                     \
        const ushort* _Bhs = _Ahs + 8192;                                     \
        const ushort* _Bls = _Ahs + 12288;                                    \
        short8 a_h[4], a_l[4], b_h[4], b_l[4];                                \
        _Pragma("unroll")                                                     \
        for (int m = 0; m < 4; ++m) {                                         \
            const int off = (wr * 64 + m * 16 + frow) * 32 + koff;            \
            a_h[m] = *(const short8*)&_Ahs[off];                              \
            a_l[m] = *(const short8*)&_Als[off];                              \
        }                                                                     \
        _Pragma("unroll")                                                     \
        for (int n = 0; n < 4; ++n) {                                         \
            const int off = (wc * 64 + n * 16 + frow) * 32 + koff;            \
            b_h[n] = *(const short8*)&_Bhs[off];                              \
            b_l[n] = *(const short8*)&_Bls[off];                              \
        }                                                                     \
        __builtin_amdgcn_s_setprio(1);                                        \
        _Pragma("unroll")                                                     \
        for (int m = 0; m < 4; ++m)                                           \
            _Pragma("unroll")                                                 \
            for (int n = 0; n < 4; ++n) {                                     \
                acc[m][n] = __builtin_amdgcn_mfma_f32_16x16x32_bf16(          \
                    a_h[m], b_h[n], acc[m][n], 0, 0, 0);                      \
                acc[m][n] = __builtin_amdgcn_mfma_f32_16x16x32_bf16(          \
                    a_h[m], b_l[n], acc[m][n], 0, 0, 0);                      \
                acc[m][n] = __builtin_amdgcn_mfma_f32_16x16x32_bf16(          \
                    a_l[m], b_h[n], acc[m][n], 0, 0, 0);                      \
            }                                                                 \
        __builtin_amdgcn_s_setprio(0);                                        \
    } while (0)

    STAGE(0, 0);
    #pragma unroll 2
    for (int t = 0; t < NT; ++t) {
        __syncthreads();
        if (t + 1 < NT) STAGE(t + 1, (t + 1) & 1);
        COMPUTE(t & 1);
    }

#undef STAGE
#undef COMPUTE

    const int crow0 = bm + wr * 64 + (lane >> 4) * 4;
    const int ccol0 = bn + wc * 64 + (lane & 15);
    #pragma unroll
    for (int m = 0; m < 4; ++m)
        #pragma unroll
        for (int n = 0; n < 4; ++n) {
            const int col = ccol0 + n * 16;
            const float bv = BIAS ? bias[col] : 0.0f;
            #pragma unroll
            for (int q = 0; q < 4; ++q) {
                float v = acc[m][n][q] + bv;
                if (RELU) v = fmaxf(v, 0.0f);
                const size_t idx = (size_t)(crow0 + m * 16 + q) * N + col;
                if (OMODE == 0) {
                    Cf[idx] = v;
                } else {
                    const ushort h = f2bf(v);
                    Ch[idx] = h;
                    Cl[idx] = f2bf(v - bf2f(h));
                }
            }
        }
}

// ================= 256x256 split-bf16 GEMM (new: lower LDS bytes/FLOP) =================
// 512 thr = 8 waves (2 rows x 4 cols), per-wave output 128x64 (8x4 16x16 frags).
// BK=32, double-buffered 128 KiB LDS, 1 block/CU, same 2-phase schedule + swizzle.
// LDS volume/FLOP = 20.3 KB/MFLOP vs 30.5 for 128^2 -> higher MfmaUtil ceiling.
template<int K, int OMODE, bool RELU, bool BIAS>
__global__ __launch_bounds__(512, 2)
void gemm256_kernel(const ushort* __restrict__ Ah, const ushort* __restrict__ Al,
                    const ushort* __restrict__ Bh, const ushort* __restrict__ Bl,
                    const float* __restrict__ bias,
                    float* __restrict__ Cf, ushort* __restrict__ Ch, ushort* __restrict__ Cl,
                    int M, int N)
{
    constexpr int NT = K / 32;
    // [buf][Ah 8192 | Al 8192 | Bh 8192 | Bl 8192] ushorts, 128 KiB total
    __shared__ __align__(16) ushort LDSB[2 * 4 * 8192];

    const int tid  = threadIdx.x;
    const int lane = tid & 63;
    const int w    = tid >> 6;
    const int wr   = w >> 2, wc = w & 3;

    int bxi = blockIdx.x, byi = blockIdx.y;
    xcd_remap(bxi, byi);
    const int bm = byi * 256, bn = bxi * 256;

    // staging: thread t covers rows {srow, 128+srow}, phys slot tid&3; source pre-swizzled
    const int    srow  = tid >> 2;                                  // 0..127
    const int    scol  = (((tid & 3) ^ ((tid >> 3) & 3)) << 3);     // ushorts
    const size_t aoffA = (size_t)(bm + srow) * K + scol;
    const size_t aoffB = (size_t)(bm + 128 + srow) * K + scol;
    const size_t boffA = (size_t)(bn + srow) * K + scol;
    const size_t boffB = (size_t)(bn + 128 + srow) * K + scol;
    const int    dst   = srow * 32 + (tid & 3) * 8;                 // ushorts (lane-linear)

    // fragment-read swizzle (0-conflict verified)
    const int frow = lane & 15;
    const int koff = ((lane >> 4) ^ ((frow >> 1) & 3)) << 3;

    f32x4 acc[8][4];
    #pragma unroll
    for (int m = 0; m < 8; ++m)
        #pragma unroll
        for (int n = 0; n < 4; ++n)
            acc[m][n] = (f32x4)0.0f;

#define STAGE256(tt, bi) do {                                                 \
        const int _kk = (tt) * 32;                                            \
        ushort* _b = &LDSB[(bi) * 32768];                                     \
        GLDS16(Ah + aoffA + _kk, _b +         dst);                           \
        GLDS16(Ah + aoffB + _kk, _b +         dst + 4096);                    \
        GLDS16(Al + aoffA + _kk, _b +  8192 + dst);                           \
        GLDS16(Al + aoffB + _kk, _b +  8192 + dst + 4096);                    \
        GLDS16(Bh + boffA + _kk, _b + 16384 + dst);                           \
        GLDS16(Bh + boffB + _kk, _b + 16384 + dst + 4096);                    \
        GLDS16(Bl + boffA + _kk, _b + 24576 + dst);                           \
        GLDS16(Bl + boffB + _kk, _b + 24576 + dst + 4096);                    \
    } while (0)

#define COMPUTE256(bi) do {                                                   \
        const ushort* _Ahs = &LDSB[(bi) * 32768];                             \
        const ushort* _Als = _Ahs + 8192;                                     \
        const ushort* _Bhs = _Ahs + 16384;                                    \
        const ushort* _Bls = _Ahs + 24576;                                    \
        short8 b_h[4], b_l[4];                                                \
        _Pragma("unroll")                                                     \
        for (int n = 0; n < 4; ++n) {                                         \
            const int off = (wc * 64 + n * 16 + frow) * 32 + koff;            \
            b_h[n] = *(const short8*)&_Bhs[off];                              \
            b_l[n] = *(const short8*)&_Bls[off];                              \
        }                                                                     \
        __builtin_amdgcn_s_setprio(1);                                        \
        _Pragma("unroll")                                                     \
        for (int m = 0; m < 8; ++m) {                                         \
            const int off = (wr * 128 + m * 16 + frow) * 32 + koff;           \
            const short8 a_h = *(const short8*)&_Ahs[off];                    \
            const short8 a_l = *(const short8*)&_Als[off];                    \
            _Pragma("unroll")                                                 \
            for (int n = 0; n < 4; ++n) {                                     \
                acc[m][n] = __builtin_amdgcn_mfma_f32_16x16x32_bf16(          \
                    a_h, b_h[n], acc[m][n], 0, 0, 0);                         \
                acc[m][n] = __builtin_amdgcn_mfma_f32_16x16x32_bf16(          \
                    a_h, b_l[n], acc[m][n], 0, 0, 0);                         \
                acc[m][n] = __builtin_amdgcn_mfma_f32_16x16x32_bf16(          \
                    a_l, b_h[n], acc[m][n], 0, 0, 0);                         \
            }                                                                 \
        }                                                                     \
        __builtin_amdgcn_s_setprio(0);                                        \
    } while (0)

    STAGE256(0, 0);
    #pragma unroll 2
    for (int t = 0; t < NT; ++t) {
        __syncthreads();                     // tile t ready; buf[(t+1)&1] free
        if (t + 1 < NT) STAGE256(t + 1, (t + 1) & 1);   // overlaps compute(t)
        COMPUTE256(t & 1);
    }

#undef STAGE256
#undef COMPUTE256

    const int crow0 = bm + wr * 128 + (lane >> 4) * 4;
    const int ccol0 = bn + wc * 64 + (lane & 15);
    #pragma unroll
    for (int m = 0; m < 8; ++m)
        #pragma unroll
        for (int n = 0; n < 4; ++n) {
            const int col = ccol0 + n * 16;
            const float bv = BIAS ? bias[col] : 0.0f;
            #pragma unroll
            for (int q = 0; q < 4; ++q) {
                float v = acc[m][n][q] + bv;
                if (RELU) v = fmaxf(v, 0.0f);
                const size_t idx = (size_t)(crow0 + m * 16 + q) * N + col;
                if (OMODE == 0) {
                    Cf[idx] = v;
                } else {
                    const ushort h = f2bf(v);
                    Ch[idx] = h;
                    Cl[idx] = f2bf(v - bf2f(h));
                }
            }
        }
}

// ---------------- per-row reduction over one sim chunk ----------------
__global__ __launch_bounds__(256) void rowreduce_kernel(
    const float* __restrict__ sim, const int* __restrict__ tgt,
    const float* __restrict__ temp_p, float* __restrict__ perrow,
    int* __restrict__ acc_cnt, int row0)
{
    const int row = blockIdx.x;
    const float* srow = sim + (size_t)row * NTXT_N;
    const int tid = threadIdx.x;

    float v[16];
    #pragma unroll
    for (int q = 0; q < 4; ++q) {
        float4 f = *(const float4*)&srow[4 * tid + 1024 * q];
        v[4 * q + 0] = f.x; v[4 * q + 1] = f.y; v[4 * q + 2] = f.z; v[4 * q + 3] = f.w;
    }

    float ss = 0.0f, mx = -3.4e38f; int mi = 0x7fffffff;
    #pragma unroll
    for (int q = 0; q < 4; ++q)
        #pragma unroll
        for (int r = 0; r < 4; ++r) {
            const int j = 4 * tid + 1024 * q + r;
            const float x = v[4 * q + r];
            ss = fmaf(x, x, ss);
            if (x > mx) { mx = x; mi = j; }
            else if (x == mx && j < mi) mi = j;
        }

    #pragma unroll
    for (int off = 32; off; off >>= 1) {
        ss += __shfl_down(ss, off);
        const float omx = __shfl_down(mx, off);
        const int   omi = __shfl_down(mi, off);
        if (omx > mx || (omx == mx && omi < mi)) { mx = omx; mi = omi; }
    }

    __shared__ float sws[4], swm[4];
    __shared__ int   swi[4];
    __shared__ float bC, bMx;
    __shared__ int   bAmax;
    const int w = tid >> 6, lane = tid & 63;
    if (lane == 0) { sws[w] = ss; swm[w] = mx; swi[w] = mi; }
    __syncthreads();
    if (tid == 0) {
        float tss = 0.0f, tmx = -3.4e38f; int tmi = 0x7fffffff;
        #pragma unroll
        for (int i = 0; i < 4; ++i) {
            tss += sws[i];
            if (swm[i] > tmx || (swm[i] == tmx && swi[i] < tmi)) { tmx = swm[i]; tmi = swi[i]; }
        }
        const float inv_nr = 1.0f / sqrtf(tss);
        const float n2 = sqrtf(tss * inv_nr * inv_nr);   // ~= 1, faithful to reference
        const float Cv = inv_nr / (n2 * temp_p[0]);
        bC = Cv; bMx = tmx * Cv; bAmax = tmi;
    }
    __syncthreads();
    const float Cv = bC, mxx = bMx;

    float es = 0.0f;
    #pragma unroll
    for (int q = 0; q < 16; ++q) es += expf(v[q] * Cv - mxx);
    #pragma unroll
    for (int off = 32; off; off >>= 1) es += __shfl_down(es, off);
    if (lane == 0) sws[w] = es;
    __syncthreads();
    if (tid == 0) {
        const float tes = sws[0] + sws[1] + sws[2] + sws[3];
        const float lse = mxx + logf(tes);
        const int t = tgt[row0 + row];
        perrow[row0 + row] = lse - srow[t] * Cv;
        if (bAmax == t) atomicAdd(acc_cnt, 1);
    }
}

// ---------------- finalize ----------------
__global__ __launch_bounds__(256) void finalize_kernel(
    const float* __restrict__ perrow, const int* __restrict__ acc_cnt,
    float* __restrict__ out)
{
    __shared__ float red[256];
    const int tid = threadIdx.x;
    float s = 0.0f;
    for (int i = tid; i < B_ROWS; i += 256) s += perrow[i];
    red[tid] = s;
    __syncthreads();
    for (int st = 128; st; st >>= 1) {
        if (tid < st) red[tid] += red[tid + st];
        __syncthreads();
    }
    if (tid == 0) {
        out[0] = red[0] / (float)B_ROWS;
        out[1] = (float)(*acc_cnt);
    }
}

extern "C" void kernel_launch(void* const* d_in, const int* in_sizes, int n_in,
                              void* d_out, int out_size, void* d_ws, size_t ws_size,
                              hipStream_t stream)
{
    const float* img  = (const float*)d_in[0];
    const float* txt  = (const float*)d_in[1];
    const int*   tgt  = (const int*)  d_in[2];
    const float* temp = (const float*)d_in[3];
    const float* Wf[6] = { (const float*)d_in[4],  (const float*)d_in[6],  (const float*)d_in[8],
                           (const float*)d_in[10], (const float*)d_in[12], (const float*)d_in[14] };
    const float* bf[6] = { (const float*)d_in[5],  (const float*)d_in[7],  (const float*)d_in[9],
                           (const float*)d_in[11], (const float*)d_in[13], (const float*)d_in[15] };
    float* out = (float*)d_out;

    // weight shapes [K, N] -> transposed hi/lo [N, K]
    const int wK[6] = { D_DIM, H_DIM, H_DIM, D_DIM, H_DIM, H_DIM };
    const int wN[6] = { H_DIM, H_DIM, D_DIM, H_DIM, H_DIM, D_DIM };

    // ---- choose chunk sizes: prefer big M for full 256-block grids ----
    auto need = [&](size_t ch, size_t sc) -> size_t {
        size_t wt = 0;
        for (int i = 0; i < 6; ++i) wt += (size_t)wK[i] * wN[i] * 2 * 2;
        const size_t a01 = 2 * (ch * H_DIM * 2 * 2);
        const size_t pt  = (size_t)NTXT_N * D_DIM * 2 * 2;
        const size_t sim = sc * NTXT_N * 4;
        return wt + a01 + pt + sim + (size_t)B_ROWS * 4 + (size_t)64 * 1024;
    };
    const size_t ladder[][2] = { {16384, 4096}, {16384, 2048}, {8192, 4096}, {8192, 2048},
                                 {4096, 2048},  {4096, 1024},  {2048, 1024}, {1024, 1024} };
    size_t CH = 1024, SIMCH = 512;
    for (auto& e : ladder)
        if (need(e[0], e[1]) <= ws_size) { CH = e[0]; SIMCH = e[1]; break; }

    // ---- carve workspace ----
    uint8_t* p = (uint8_t*)d_ws;
    auto alloc = [&](size_t bytes) -> void* {
        void* r = (void*)p; p += (bytes + 255) & ~(size_t)255; return r;
    };
    ushort* WTh[6]; ushort* WTl[6];
    for (int i = 0; i < 6; ++i) {
        WTh[i] = (ushort*)alloc((size_t)wK[i] * wN[i] * 2);
        WTl[i] = (ushort*)alloc((size_t)wK[i] * wN[i] * 2);
    }
    ushort* A0h = (ushort*)alloc(CH * H_DIM * 2);
    ushort* A0l = (ushort*)alloc(CH * H_DIM * 2);
    ushort* A1h = (ushort*)alloc(CH * H_DIM * 2);
    ushort* A1l = (ushort*)alloc(CH * H_DIM * 2);
    ushort* PTh = (ushort*)alloc((size_t)NTXT_N * D_DIM * 2);
    ushort* PTl = (ushort*)alloc((size_t)NTXT_N * D_DIM * 2);
    float*  SIM = (float*)alloc(SIMCH * NTXT_N * 4);
    float*  PERROW = (float*)alloc((size_t)B_ROWS * 4);
    int*    ACC = (int*)alloc(64);
    ushort* XBh = A1h;  ushort* XBl = A1l;      // input chunk alias
    ushort* PIh = A0h;  ushort* PIl = A0l;      // p_img chunk alias

    init_kernel<<<1, 64, 0, stream>>>(ACC);

    // ---- weight transpose+split ----
    for (int i = 0; i < 6; ++i)
        tsplit_kernel<<<dim3(wN[i] / 32, wK[i] / 32), dim3(32, 8), 0, stream>>>(
            Wf[i], WTh[i], WTl[i], wK[i], wN[i], 0);

    // ---- txt MLP: p_txt = MLP(txt^T), chunked (128^2 kernel: grids stay full) ----
    const size_t CHT = CH < (size_t)NTXT_N ? CH : (size_t)NTXT_N;
    for (size_t n0 = 0; n0 < NTXT_N; n0 += CHT) {
        tsplit_kernel<<<dim3(CHT / 32, D_DIM / 32), dim3(32, 8), 0, stream>>>(
            txt, XBh, XBl, D_DIM, NTXT_N, (int)n0);
        gemm_p2_kernel<D_DIM, 1, true, true><<<dim3(H_DIM / 128, CHT / 128), 256, 0, stream>>>(
            XBh, XBl, WTh[3], WTl[3], bf[3], nullptr, A0h, A0l, (int)CHT, H_DIM);
        gemm_p2_kernel<H_DIM, 1, true, true><<<dim3(H_DIM / 128, CHT / 128), 256, 0, stream>>>(
            A0h, A0l, WTh[4], WTl[4], bf[4], nullptr, A1h, A1l, (int)CHT, H_DIM);
        gemm_p2_kernel<H_DIM, 1, false, true><<<dim3(D_DIM / 128, CHT / 128), 256, 0, stream>>>(
            A1h, A1l, WTh[5], WTl[5], bf[5], nullptr,
            PTh + n0 * D_DIM, PTl + n0 * D_DIM, (int)CHT, D_DIM);
    }

    // ---- img MLP + fused sim/loss, chunked ----
    const bool big = (CH % 256 == 0) && (CH >= 4096);
    for (size_t m0 = 0; m0 < B_ROWS; m0 += CH) {
        csplit_kernel<<<(CH * D_DIM / 4 + 255) / 256, 256, 0, stream>>>(
            img + m0 * D_DIM, XBh, XBl, (int)(CH * D_DIM));
        if (big) {
            gemm256_kernel<D_DIM, 1, true, true><<<dim3(H_DIM / 256, CH / 256), 512, 0, stream>>>(
                XBh, XBl, WTh[0], WTl[0], bf[0], nullptr, A0h, A0l, (int)CH, H_DIM);
            gemm256_kernel<H_DIM, 1, true, true><<<dim3(H_DIM / 256, CH / 256), 512, 0, stream>>>(
                A0h, A0l, WTh[1], WTl[1], bf[1], nullptr, A1h, A1l, (int)CH, H_DIM);
        } else {
            gemm_p2_kernel<D_DIM, 1, true, true><<<dim3(H_DIM / 128, CH / 128), 256, 0, stream>>>(
                XBh, XBl, WTh[0], WTl[0], bf[0], nullptr, A0h, A0l, (int)CH, H_DIM);
            gemm_p2_kernel<H_DIM, 1, true, true><<<dim3(H_DIM / 128, CH / 128), 256, 0, stream>>>(
                A0h, A0l, WTh[1], WTl[1], bf[1], nullptr, A1h, A1l, (int)CH, H_DIM);
        }
        gemm_p2_kernel<H_DIM, 1, false, true><<<dim3(D_DIM / 128, CH / 128), 256, 0, stream>>>(
            A1h, A1l, WTh[2], WTl[2], bf[2], nullptr, PIh, PIl, (int)CH, D_DIM);
        for (size_t s0 = 0; s0 < CH; s0 += SIMCH) {
            if ((SIMCH % 256 == 0) && SIMCH >= 2048) {
                gemm256_kernel<D_DIM, 0, false, false><<<dim3(NTXT_N / 256, SIMCH / 256), 512, 0, stream>>>(
                    PIh + s0 * D_DIM, PIl + s0 * D_DIM, PTh, PTl, nullptr,
                    SIM, nullptr, nullptr, (int)SIMCH, NTXT_N);
            } else {
                gemm_p2_kernel<D_DIM, 0, false, false><<<dim3(NTXT_N / 128, SIMCH / 128), 256, 0, stream>>>(
                    PIh + s0 * D_DIM, PIl + s0 * D_DIM, PTh, PTl, nullptr,
                    SIM, nullptr, nullptr, (int)SIMCH, NTXT_N);
            }
            rowreduce_kernel<<<SIMCH, 256, 0, stream>>>(
                SIM, tgt, temp, PERROW, ACC, (int)(m0 + s0));
        }
    }

    finalize_kernel<<<1, 256, 0, stream>>>(PERROW, ACC, out);
}